// Round 4
// baseline (2145.717 us; speedup 1.0000x reference)
//
#include <hip/hip_runtime.h>
#include <math.h>

#define NRAYS 16384
#define NC    64
#define NF    128
#define NZ    192   // NC + NF
#define H     64

__device__ __forceinline__ float wave_incl_scan(float v, int lane) {
#pragma unroll
  for (int off = 1; off < 64; off <<= 1) {
    float n = __shfl_up(v, off);
    v = (lane >= off) ? v + n : v;
  }
  return v;
}

// Exact running max (order-insensitive) — forces the CDF non-decreasing
// despite fp non-associativity of the shuffle +-scan.
__device__ __forceinline__ float wave_incl_max_scan(float v, int lane) {
#pragma unroll
  for (int off = 1; off < 64; off <<= 1) {
    float n = __shfl_up(v, off);
    v = (lane >= off) ? fmaxf(v, n) : v;
  }
  return v;
}

__device__ __forceinline__ float wave_sum(float v) {
#pragma unroll
  for (int off = 32; off > 0; off >>= 1) v += __shfl_xor(v, off);
  return v;
}

struct __align__(16) WLds {
  float W1b[H][4];   // {w1[0][j], w1[1][j], w1[2][j], b1[j]}
  float B2[H];
  float W2T[H][H];   // [j][k] = w2[k][j]
  float Head[H][4];  // {wr[j][0..2], wd[j]}
};

__device__ __forceinline__ void load_weights_lds(
    int tid,
    const float* __restrict__ w1, const float* __restrict__ b1,
    const float* __restrict__ w2, const float* __restrict__ b2,
    const float* __restrict__ wr, const float* __restrict__ wd,
    WLds& W)
{
  if (tid < H) {
    int j = tid;
    W.W1b[j][0] = w1[0*H + j];
    W.W1b[j][1] = w1[1*H + j];
    W.W1b[j][2] = w1[2*H + j];
    W.W1b[j][3] = b1[j];
    W.B2[j]     = b2[j];
    W.Head[j][0] = wr[j*3 + 0];
    W.Head[j][1] = wr[j*3 + 1];
    W.Head[j][2] = wr[j*3 + 2];
    W.Head[j][3] = wd[j];
  }
  for (int e = tid; e < H*H; e += 256) {
    int k = e >> 6, j = e & 63;   // w2 row-major [k][j]
    W.W2T[j][k] = w2[e];
  }
}

// Per-lane full MLP. h1 in registers; layer2+heads fused, wave-uniform
// (broadcast) LDS reads -> no bank conflicts.
__device__ __forceinline__ void mlp_eval(
    float x0, float x1, float x2, const WLds& W,
    float hb0, float hb1, float hb2, float hbd,
    float& r0o, float& r1o, float& r2o, float& dno)
{
  float h1[H];
#pragma unroll
  for (int j = 0; j < H; ++j) {
    const float4 wv = *(const float4*)(&W.W1b[j][0]);
    float a = fmaf(x0, wv.x, fmaf(x1, wv.y, fmaf(x2, wv.z, wv.w)));
    h1[j] = fmaxf(a, 0.f);
  }
  float r0 = hb0, r1 = hb1, r2 = hb2, dn = hbd;
#pragma unroll 2
  for (int j = 0; j < H; ++j) {
    float acc = W.B2[j];
    const float4* wrow = (const float4*)(&W.W2T[j][0]);
#pragma unroll
    for (int k4 = 0; k4 < H/4; ++k4) {
      const float4 wv = wrow[k4];
      acc = fmaf(h1[4*k4+0], wv.x, acc);
      acc = fmaf(h1[4*k4+1], wv.y, acc);
      acc = fmaf(h1[4*k4+2], wv.z, acc);
      acc = fmaf(h1[4*k4+3], wv.w, acc);
    }
    const float h2v = fmaxf(acc, 0.f);
    const float4 hw = *(const float4*)(&W.Head[j][0]);
    r0 = fmaf(h2v, hw.x, r0);
    r1 = fmaf(h2v, hw.y, r1);
    r2 = fmaf(h2v, hw.z, r2);
    dn = fmaf(h2v, hw.w, dn);
  }
  r0o = 1.f / (1.f + expf(-r0));
  r1o = 1.f / (1.f + expf(-r1));
  r2o = 1.f / (1.f + expf(-r2));
  dno = fmaxf(dn, 0.f);
}

// Coarse pass for one ray, executed by ONE wave (no block barriers inside!).
// Writes the merged 192-entry z row into zdst (LDS). If emit, writes the
// coarse half of this ray's output row. Scratch arrays are wave-private LDS.
__device__ __forceinline__ void coarse_pass(
    int ray, int lane,
    const float* __restrict__ origins, const float* __restrict__ dirs,
    const float* __restrict__ nearp, const float* __restrict__ farp,
    const float* __restrict__ bkgd,
    const WLds& W, float hb0, float hb1, float hb2, float hbd,
    float* __restrict__ sT, float* __restrict__ sBins,
    float* __restrict__ sCdf, float* __restrict__ sZs,
    float* __restrict__ zdst, bool emit, float* __restrict__ out)
{
  const float nearv = nearp[ray];
  const float farv  = farp[ray];
  const float ox = origins[ray*3+0], oy = origins[ray*3+1], oz = origins[ray*3+2];
  const float dx = dirs[ray*3+0],    dy = dirs[ray*3+1],    dz = dirs[ray*3+2];

  // exact linspace endpoints: u = lane/63
  const float u_i  = (float)lane / 63.0f;
  const float u_n  = (float)(lane + 1) / 63.0f;
  const float tv    = nearv * (1.f - u_i) + farv * u_i;
  const float tnext = nearv * (1.f - u_n) + farv * u_n;

  sT[lane] = tv;
  if (lane < NC-1) sBins[lane] = 0.5f * (tv + tnext);
  // defensively zero the merge destination (bijective merge should cover all)
  zdst[lane] = 0.f; zdst[lane+64] = 0.f; zdst[lane+128] = 0.f;

  float rgb0, rgb1, rgb2, dens;
  mlp_eval(ox + tv*dx, oy + tv*dy, oz + tv*dz, W, hb0, hb1, hb2, hbd,
           rgb0, rgb1, rgb2, dens);

  const float dnorm = sqrtf(dx*dx + dy*dy + dz*dz);
  const float tdist = (lane == NC-1) ? 1e10f : (tnext - tv);
  // clamp: exp(-1e4)==exp(-anything bigger)==0 in fp32; prevents inf-inf NaN
  const float dd    = fminf(dens * (tdist * dnorm), 1e4f);
  const float incl  = wave_incl_scan(dd, lane);
  const float excl  = incl - dd;
  const float alpha = 1.f - expf(-dd);
  const float trans = expf(-excl);
  const float w     = alpha * trans;

  if (emit) {
    // ray-0 t_vals for the samples[0] quirk in pts0
    const float near0 = nearp[0], far0 = farp[0];
    const float t0v   = near0 * (1.f - u_i) + far0 * u_i;
    const float s_w   = wave_sum(w);
    const float s_wt  = wave_sum(w * tv);
    const float s_c0  = wave_sum(w * rgb0);
    const float s_c1  = wave_sum(w * rgb1);
    const float s_c2  = wave_sum(w * rgb2);
    const float s_wt0 = wave_sum(w * t0v);
    if (lane == 0) {
      const float bk0 = bkgd[0], bk1 = bkgd[1], bk2 = bkgd[2];
      const float o0x = origins[0], o0y = origins[1], o0z = origins[2];
      const float d0x = dirs[0],    d0y = dirs[1],    d0z = dirs[2];
      const float oma = 1.f - s_w;
      float* o = out + (size_t)ray * 16;
      o[0] = s_c0 + bk0 * oma;
      o[1] = s_c1 + bk1 * oma;
      o[2] = s_c2 + bk2 * oma;
      o[3] = s_wt;                       // depth0
      o[4] = s_w;                        // acc0
      o[5] = s_w * o0x + s_wt0 * d0x;    // pts0
      o[6] = s_w * o0y + s_wt0 * d0y;
      o[7] = s_w * o0z + s_wt0 * d0z;
    }
  }

  // ---- piecewise-constant PDF -> CDF (62 weights = w[1..62]) ----
  const float wnext = __shfl_down(w, 1);
  const float pw = (lane < NC-2) ? wnext : 0.f;
  const float ws_sum = wave_sum(pw);
  const float pad = fmaxf(1e-5f - ws_sum, 0.f);
  const float wsp = ws_sum + pad;
  const float pdf = (lane < NC-2) ? (pw + pad * (1.f/62.f)) / wsp : 0.f;
  float ip  = wave_incl_scan(pdf, lane);
  ip = wave_incl_max_scan(ip, lane);       // exact monotone
  if (lane < 61)  sCdf[lane+1] = fminf(ip, 1.f);
  if (lane == 61) sCdf[0]  = 0.f;
  if (lane == 62) sCdf[62] = 1.f;
  __builtin_amdgcn_wave_barrier();         // order LDS writes before reads (same wave)

  // ---- inverse-CDF: 128 samples, 2 per lane ----
  const float ustep = (1.0f - 1.1920929e-07f) / 127.0f;
#pragma unroll
  for (int r = 0; r < 2; ++r) {
    const int k = lane + 64*r;
    const float u = k * ustep;
    int lo = 0, hi = 61;                   // largest J with cdf[J] <= u
    while (lo < hi) {
      const int mid = (lo + hi + 1) >> 1;
      if (sCdf[mid] <= u) lo = mid; else hi = mid - 1;
    }
    const int J = lo;
    const float cg0 = sCdf[J],  cg1 = sCdf[J+1];
    const float bg0 = sBins[J], bg1 = sBins[J+1];
    const float denom = cg1 - cg0;
    const float num   = u - cg0;
    float tt;
    if (denom > 0.f) tt = fminf(fmaxf(num / denom, 0.f), 1.f);
    else             tt = (num > 0.f) ? 1.f : 0.f;
    sZs[k] = fmaf(tt, bg1 - bg0, bg0);
  }
  __builtin_amdgcn_wave_barrier();

  // ---- stable rank merge of sorted t (64) and z (128) into zdst (192) ----
  {
    int l = 0, r = NF;                     // count z < tv
    while (l < r) { const int m = (l + r) >> 1; if (sZs[m] < tv) l = m + 1; else r = m; }
    zdst[lane + l] = tv;
  }
#pragma unroll
  for (int r2 = 0; r2 < 2; ++r2) {
    const int k = lane + 64*r2;
    const float z = sZs[k];
    int l = 0, r = NC;                     // count t <= z
    while (l < r) { const int m = (l + r) >> 1; if (sT[m] <= z) l = m + 1; else r = m; }
    zdst[k + l] = z;
  }
  __builtin_amdgcn_wave_barrier();
}

// ---------------- Fused kernel: 4 waves = 4 rays per block, no global scratch
__global__ __launch_bounds__(256) void nerf_fused_kernel(
    const float* __restrict__ origins, const float* __restrict__ dirs,
    const float* __restrict__ nearp, const float* __restrict__ farp,
    const float* __restrict__ bkgd,
    const float* __restrict__ w1c, const float* __restrict__ b1c,
    const float* __restrict__ w2c, const float* __restrict__ b2c,
    const float* __restrict__ wrc, const float* __restrict__ brc,
    const float* __restrict__ wdc, const float* __restrict__ bdc,
    const float* __restrict__ w1f, const float* __restrict__ b1f,
    const float* __restrict__ w2f, const float* __restrict__ b2f_,
    const float* __restrict__ wrf, const float* __restrict__ brf,
    const float* __restrict__ wdf, const float* __restrict__ bdf,
    float* __restrict__ out)
{
  __shared__ WLds sWc, sWf;
  __shared__ float sT[4][NC];
  __shared__ float sBins[4][NC];
  __shared__ float sCdf[4][NC];
  __shared__ float sZs[4][NF];
  __shared__ float sZv[4][NZ];
  __shared__ float sZv0[NZ];     // ray 0's fine z row (samples_f[0] quirk)

  const int tid  = threadIdx.x;
  const int wv   = tid >> 6;
  const int lane = tid & 63;
  const int ray  = blockIdx.x * 4 + wv;

  load_weights_lds(tid, w1c, b1c, w2c, b2c, wrc, wdc, sWc);
  load_weights_lds(tid, w1f, b1f, w2f, b2f_, wrf, wdf, sWf);
  __syncthreads();

  const float cb0 = brc[0], cb1 = brc[1], cb2 = brc[2], cbd = bdc[0];
  const float fb0 = brf[0], fb1 = brf[1], fb2 = brf[2], fbd = bdf[0];

  // own coarse pass -> own z row + coarse outputs
  coarse_pass(ray, lane, origins, dirs, nearp, farp, bkgd,
              sWc, cb0, cb1, cb2, cbd,
              sT[wv], sBins[wv], sCdf[wv], sZs[wv], sZv[wv], true, out);

  // wave 0 recomputes ray 0's z row for this block (deterministic, bit-identical)
  if (wv == 0) {
    coarse_pass(0, lane, origins, dirs, nearp, farp, bkgd,
                sWc, cb0, cb1, cb2, cbd,
                sT[0], sBins[0], sCdf[0], sZs[0], sZv0, false, out);
  }

  // ---- fine pass: 3 samples per lane ----
  const float ox = origins[ray*3+0], oy = origins[ray*3+1], oz = origins[ray*3+2];
  const float dx = dirs[ray*3+0],    dy = dirs[ray*3+1],    dz = dirs[ray*3+2];
  const float dnorm = sqrtf(dx*dx + dy*dy + dz*dz);

  float zc[3], zn[3];
#pragma unroll
  for (int s = 0; s < 3; ++s) {
    const int i = lane + 64*s;
    zc[s] = sZv[wv][i];
    zn[s] = (i < NZ-1) ? sZv[wv][i+1] : 0.f;
  }

  float rr0[3], rr1[3], rr2[3], dens[3];
#pragma unroll
  for (int s = 0; s < 3; ++s) {
    mlp_eval(ox + zc[s]*dx, oy + zc[s]*dy, oz + zc[s]*dz, sWf,
             fb0, fb1, fb2, fbd, rr0[s], rr1[s], rr2[s], dens[s]);
  }

  float dd[3];
#pragma unroll
  for (int s = 0; s < 3; ++s) {
    const int i = lane + 64*s;
    const float td = (i == NZ-1) ? 1e10f : fmaxf(zn[s] - zc[s], 0.f);
    dd[s] = fminf(dens[s] * (td * dnorm), 1e4f);
  }

  float excl[3];
  float offset = 0.f;
#pragma unroll
  for (int s = 0; s < 3; ++s) {
    const float incl = wave_incl_scan(dd[s], lane);
    excl[s] = offset + incl - dd[s];
    offset += __shfl(incl, 63);
  }

  __syncthreads();   // sZv0 ready (wave 0 wrote it above)

  float aw = 0.f, awz = 0.f, ac0 = 0.f, ac1 = 0.f, ac2 = 0.f, awz0 = 0.f;
#pragma unroll
  for (int s = 0; s < 3; ++s) {
    const int i = lane + 64*s;
    const float wgt = (1.f - expf(-dd[s])) * expf(-excl[s]);
    aw   += wgt;
    awz  += wgt * zc[s];
    ac0  += wgt * rr0[s];
    ac1  += wgt * rr1[s];
    ac2  += wgt * rr2[s];
    awz0 += wgt * sZv0[i];
  }
  aw  = wave_sum(aw);  awz = wave_sum(awz); ac0 = wave_sum(ac0);
  ac1 = wave_sum(ac1); ac2 = wave_sum(ac2); awz0 = wave_sum(awz0);

  if (lane == 0) {
    const float bk0 = bkgd[0], bk1 = bkgd[1], bk2 = bkgd[2];
    const float o0x = origins[0], o0y = origins[1], o0z = origins[2];
    const float d0x = dirs[0],    d0y = dirs[1],    d0z = dirs[2];
    const float oma = 1.f - aw;
    float* o = out + (size_t)ray * 16 + 8;
    o[0] = ac0 + bk0 * oma;
    o[1] = ac1 + bk1 * oma;
    o[2] = ac2 + bk2 * oma;
    o[3] = awz;                        // depth1
    o[4] = aw;                         // acc1
    o[5] = aw * o0x + awz0 * d0x;      // pts1
    o[6] = aw * o0y + awz0 * d0y;
    o[7] = aw * o0z + awz0 * d0z;
  }
}

extern "C" void kernel_launch(void* const* d_in, const int* in_sizes, int n_in,
                              void* d_out, int out_size, void* d_ws, size_t ws_size,
                              hipStream_t stream) {
  const float* origins = (const float*)d_in[0];
  const float* dirs    = (const float*)d_in[1];
  const float* nearp   = (const float*)d_in[2];
  const float* farp    = (const float*)d_in[3];
  const float* bkgd    = (const float*)d_in[4];
  const float* w1c  = (const float*)d_in[5];
  const float* b1c  = (const float*)d_in[6];
  const float* w2c  = (const float*)d_in[7];
  const float* b2c  = (const float*)d_in[8];
  const float* wrc  = (const float*)d_in[9];
  const float* brc  = (const float*)d_in[10];
  const float* wdc  = (const float*)d_in[11];
  const float* bdc  = (const float*)d_in[12];
  const float* w1f  = (const float*)d_in[13];
  const float* b1f  = (const float*)d_in[14];
  const float* w2f  = (const float*)d_in[15];
  const float* b2f_ = (const float*)d_in[16];
  const float* wrf  = (const float*)d_in[17];
  const float* brf  = (const float*)d_in[18];
  const float* wdf  = (const float*)d_in[19];
  const float* bdf  = (const float*)d_in[20];

  nerf_fused_kernel<<<NRAYS/4, 256, 0, stream>>>(
      origins, dirs, nearp, farp, bkgd,
      w1c, b1c, w2c, b2c, wrc, brc, wdc, bdc,
      w1f, b1f, w2f, b2f_, wrf, brf, wdf, bdf,
      (float*)d_out);
}

// Round 5
// 930.678 us; speedup vs baseline: 2.3055x; 2.3055x over previous
//
#include <hip/hip_runtime.h>
#include <math.h>

#define NRAYS 16384
#define NC    64
#define NF    128
#define NZ    192   // NC + NF
#define H     64

__device__ __forceinline__ float wave_incl_scan(float v, int lane) {
#pragma unroll
  for (int off = 1; off < 64; off <<= 1) {
    float n = __shfl_up(v, off);
    v = (lane >= off) ? v + n : v;
  }
  return v;
}

// Exact running max (order-insensitive) — forces the CDF non-decreasing
// despite fp non-associativity of the shuffle +-scan.
__device__ __forceinline__ float wave_incl_max_scan(float v, int lane) {
#pragma unroll
  for (int off = 1; off < 64; off <<= 1) {
    float n = __shfl_up(v, off);
    v = (lane >= off) ? fmaxf(v, n) : v;
  }
  return v;
}

__device__ __forceinline__ float wave_sum(float v) {
#pragma unroll
  for (int off = 32; off > 0; off >>= 1) v += __shfl_xor(v, off);
  return v;
}

// Small wave-uniform weights staged in LDS (broadcast reads, cheap).
// W2 (64x64) is deliberately NOT staged: it is read straight from global
// with wave-uniform addresses -> scalar loads (SGPR broadcast), keeping the
// 16KB-per-batch weight stream OFF the LDS pipe (which was the R4 bottleneck).
struct __align__(16) WLds {
  float W1b[H][4];   // {w1[0][j], w1[1][j], w1[2][j], b1[j]}
  float B2[H];
  float Head[H][4];  // {wr[j][0..2], wd[j]}
};

__device__ __forceinline__ void load_weights_lds(
    int tid,
    const float* __restrict__ w1, const float* __restrict__ b1,
    const float* __restrict__ b2,
    const float* __restrict__ wr, const float* __restrict__ wd,
    WLds& W)
{
  if (tid < H) {
    int j = tid;
    W.W1b[j][0] = w1[0*H + j];
    W.W1b[j][1] = w1[1*H + j];
    W.W1b[j][2] = w1[2*H + j];
    W.W1b[j][3] = b1[j];
    W.B2[j]     = b2[j];
    W.Head[j][0] = wr[j*3 + 0];
    W.Head[j][1] = wr[j*3 + 1];
    W.Head[j][2] = wr[j*3 + 2];
    W.Head[j][3] = wd[j];
  }
}

// Per-lane full MLP, layer1 fused into the k-loop (no persistent h1[]):
//   h2[j] (64 regs) accumulates b2 + sum_k relu(x.w1[:,k]+b1[k]) * w2[k][j]
// w2 row reads are wave-uniform global loads -> scalar path, not LDS.
__device__ __forceinline__ void mlp_eval(
    float x0, float x1, float x2, const WLds& W,
    const float* __restrict__ w2,
    float hb0, float hb1, float hb2, float hbd,
    float& r0o, float& r1o, float& r2o, float& dno)
{
  float h2[H];
#pragma unroll
  for (int j = 0; j < H; ++j) h2[j] = W.B2[j];

#pragma unroll 8
  for (int k = 0; k < H; ++k) {
    const float4 wv = *(const float4*)(&W.W1b[k][0]);
    const float h1k =
        fmaxf(fmaf(x0, wv.x, fmaf(x1, wv.y, fmaf(x2, wv.z, wv.w))), 0.f);
    const float* __restrict__ wrow = w2 + k * H;   // uniform address
#pragma unroll
    for (int j = 0; j < H; ++j) h2[j] = fmaf(h1k, wrow[j], h2[j]);
  }

  float r0 = hb0, r1 = hb1, r2 = hb2, dn = hbd;
#pragma unroll 8
  for (int j = 0; j < H; ++j) {
    const float h2v = fmaxf(h2[j], 0.f);
    const float4 hw = *(const float4*)(&W.Head[j][0]);
    r0 = fmaf(h2v, hw.x, r0);
    r1 = fmaf(h2v, hw.y, r1);
    r2 = fmaf(h2v, hw.z, r2);
    dn = fmaf(h2v, hw.w, dn);
  }
  r0o = 1.f / (1.f + expf(-r0));
  r1o = 1.f / (1.f + expf(-r1));
  r2o = 1.f / (1.f + expf(-r2));
  dno = fmaxf(dn, 0.f);
}

// Coarse pass for one ray, executed by ONE wave (no block barriers inside!).
// Writes the merged 192-entry z row into zdst (LDS). If emit, writes the
// coarse half of this ray's output row. Scratch arrays are wave-private LDS.
__device__ __forceinline__ void coarse_pass(
    int ray, int lane,
    const float* __restrict__ origins, const float* __restrict__ dirs,
    const float* __restrict__ nearp, const float* __restrict__ farp,
    const float* __restrict__ bkgd,
    const WLds& W, const float* __restrict__ w2,
    float hb0, float hb1, float hb2, float hbd,
    float* __restrict__ sT, float* __restrict__ sBins,
    float* __restrict__ sCdf, float* __restrict__ sZs,
    float* __restrict__ zdst, bool emit, float* __restrict__ out)
{
  const float nearv = nearp[ray];
  const float farv  = farp[ray];
  const float ox = origins[ray*3+0], oy = origins[ray*3+1], oz = origins[ray*3+2];
  const float dx = dirs[ray*3+0],    dy = dirs[ray*3+1],    dz = dirs[ray*3+2];

  // exact linspace endpoints: u = lane/63
  const float u_i  = (float)lane / 63.0f;
  const float u_n  = (float)(lane + 1) / 63.0f;
  const float tv    = nearv * (1.f - u_i) + farv * u_i;
  const float tnext = nearv * (1.f - u_n) + farv * u_n;

  sT[lane] = tv;
  if (lane < NC-1) sBins[lane] = 0.5f * (tv + tnext);
  // defensively zero the merge destination (bijective merge should cover all)
  zdst[lane] = 0.f; zdst[lane+64] = 0.f; zdst[lane+128] = 0.f;

  float rgb0, rgb1, rgb2, dens;
  mlp_eval(ox + tv*dx, oy + tv*dy, oz + tv*dz, W, w2, hb0, hb1, hb2, hbd,
           rgb0, rgb1, rgb2, dens);

  const float dnorm = sqrtf(dx*dx + dy*dy + dz*dz);
  const float tdist = (lane == NC-1) ? 1e10f : (tnext - tv);
  // clamp: exp(-1e4)==exp(-anything bigger)==0 in fp32; prevents inf-inf NaN
  const float dd    = fminf(dens * (tdist * dnorm), 1e4f);
  const float incl  = wave_incl_scan(dd, lane);
  const float excl  = incl - dd;
  const float alpha = 1.f - expf(-dd);
  const float trans = expf(-excl);
  const float w     = alpha * trans;

  if (emit) {
    // ray-0 t_vals for the samples[0] quirk in pts0
    const float near0 = nearp[0], far0 = farp[0];
    const float t0v   = near0 * (1.f - u_i) + far0 * u_i;
    const float s_w   = wave_sum(w);
    const float s_wt  = wave_sum(w * tv);
    const float s_c0  = wave_sum(w * rgb0);
    const float s_c1  = wave_sum(w * rgb1);
    const float s_c2  = wave_sum(w * rgb2);
    const float s_wt0 = wave_sum(w * t0v);
    if (lane == 0) {
      const float bk0 = bkgd[0], bk1 = bkgd[1], bk2 = bkgd[2];
      const float o0x = origins[0], o0y = origins[1], o0z = origins[2];
      const float d0x = dirs[0],    d0y = dirs[1],    d0z = dirs[2];
      const float oma = 1.f - s_w;
      float* o = out + (size_t)ray * 16;
      o[0] = s_c0 + bk0 * oma;
      o[1] = s_c1 + bk1 * oma;
      o[2] = s_c2 + bk2 * oma;
      o[3] = s_wt;                       // depth0
      o[4] = s_w;                        // acc0
      o[5] = s_w * o0x + s_wt0 * d0x;    // pts0
      o[6] = s_w * o0y + s_wt0 * d0y;
      o[7] = s_w * o0z + s_wt0 * d0z;
    }
  }

  // ---- piecewise-constant PDF -> CDF (62 weights = w[1..62]) ----
  const float wnext = __shfl_down(w, 1);
  const float pw = (lane < NC-2) ? wnext : 0.f;
  const float ws_sum = wave_sum(pw);
  const float pad = fmaxf(1e-5f - ws_sum, 0.f);
  const float wsp = ws_sum + pad;
  const float pdf = (lane < NC-2) ? (pw + pad * (1.f/62.f)) / wsp : 0.f;
  float ip  = wave_incl_scan(pdf, lane);
  ip = wave_incl_max_scan(ip, lane);       // exact monotone
  if (lane < 61)  sCdf[lane+1] = fminf(ip, 1.f);
  if (lane == 61) sCdf[0]  = 0.f;
  if (lane == 62) sCdf[62] = 1.f;
  __builtin_amdgcn_wave_barrier();         // order LDS writes before reads (same wave)

  // ---- inverse-CDF: 128 samples, 2 per lane ----
  const float ustep = (1.0f - 1.1920929e-07f) / 127.0f;
#pragma unroll
  for (int r = 0; r < 2; ++r) {
    const int k = lane + 64*r;
    const float u = k * ustep;
    int lo = 0, hi = 61;                   // largest J with cdf[J] <= u
    while (lo < hi) {
      const int mid = (lo + hi + 1) >> 1;
      if (sCdf[mid] <= u) lo = mid; else hi = mid - 1;
    }
    const int J = lo;
    const float cg0 = sCdf[J],  cg1 = sCdf[J+1];
    const float bg0 = sBins[J], bg1 = sBins[J+1];
    const float denom = cg1 - cg0;
    const float num   = u - cg0;
    float tt;
    if (denom > 0.f) tt = fminf(fmaxf(num / denom, 0.f), 1.f);
    else             tt = (num > 0.f) ? 1.f : 0.f;
    sZs[k] = fmaf(tt, bg1 - bg0, bg0);
  }
  __builtin_amdgcn_wave_barrier();

  // ---- stable rank merge of sorted t (64) and z (128) into zdst (192) ----
  {
    int l = 0, r = NF;                     // count z < tv
    while (l < r) { const int m = (l + r) >> 1; if (sZs[m] < tv) l = m + 1; else r = m; }
    zdst[lane + l] = tv;
  }
#pragma unroll
  for (int r2 = 0; r2 < 2; ++r2) {
    const int k = lane + 64*r2;
    const float z = sZs[k];
    int l = 0, r = NC;                     // count t <= z
    while (l < r) { const int m = (l + r) >> 1; if (sT[m] <= z) l = m + 1; else r = m; }
    zdst[k + l] = z;
  }
  __builtin_amdgcn_wave_barrier();
}

// ---------------- Fused kernel: 4 waves = 4 rays per block, no global scratch
__global__ __launch_bounds__(256) void nerf_fused_kernel(
    const float* __restrict__ origins, const float* __restrict__ dirs,
    const float* __restrict__ nearp, const float* __restrict__ farp,
    const float* __restrict__ bkgd,
    const float* __restrict__ w1c, const float* __restrict__ b1c,
    const float* __restrict__ w2c, const float* __restrict__ b2c,
    const float* __restrict__ wrc, const float* __restrict__ brc,
    const float* __restrict__ wdc, const float* __restrict__ bdc,
    const float* __restrict__ w1f, const float* __restrict__ b1f,
    const float* __restrict__ w2f, const float* __restrict__ b2f_,
    const float* __restrict__ wrf, const float* __restrict__ brf,
    const float* __restrict__ wdf, const float* __restrict__ bdf,
    float* __restrict__ out)
{
  __shared__ WLds sWc, sWf;
  __shared__ float sT[4][NC];
  __shared__ float sBins[4][NC];
  __shared__ float sCdf[4][NC];
  __shared__ float sZs[4][NF];
  __shared__ float sZv[4][NZ];
  __shared__ float sZv0[NZ];     // ray 0's fine z row (samples_f[0] quirk)

  const int tid  = threadIdx.x;
  const int wv   = tid >> 6;
  const int lane = tid & 63;
  const int ray  = blockIdx.x * 4 + wv;

  load_weights_lds(tid, w1c, b1c, b2c, wrc, wdc, sWc);
  load_weights_lds(tid, w1f, b1f, b2f_, wrf, wdf, sWf);
  __syncthreads();

  const float cb0 = brc[0], cb1 = brc[1], cb2 = brc[2], cbd = bdc[0];
  const float fb0 = brf[0], fb1 = brf[1], fb2 = brf[2], fbd = bdf[0];

  // own coarse pass -> own z row + coarse outputs
  coarse_pass(ray, lane, origins, dirs, nearp, farp, bkgd,
              sWc, w2c, cb0, cb1, cb2, cbd,
              sT[wv], sBins[wv], sCdf[wv], sZs[wv], sZv[wv], true, out);

  // wave 0 recomputes ray 0's z row for this block (deterministic, bit-identical)
  if (wv == 0) {
    coarse_pass(0, lane, origins, dirs, nearp, farp, bkgd,
                sWc, w2c, cb0, cb1, cb2, cbd,
                sT[0], sBins[0], sCdf[0], sZs[0], sZv0, false, out);
  }

  // ---- fine pass: 3 samples per lane ----
  const float ox = origins[ray*3+0], oy = origins[ray*3+1], oz = origins[ray*3+2];
  const float dx = dirs[ray*3+0],    dy = dirs[ray*3+1],    dz = dirs[ray*3+2];
  const float dnorm = sqrtf(dx*dx + dy*dy + dz*dz);

  float zc[3], zn[3];
#pragma unroll
  for (int s = 0; s < 3; ++s) {
    const int i = lane + 64*s;
    zc[s] = sZv[wv][i];
    zn[s] = (i < NZ-1) ? sZv[wv][i+1] : 0.f;
  }

  float rr0[3], rr1[3], rr2[3], dens[3];
#pragma unroll
  for (int s = 0; s < 3; ++s) {
    mlp_eval(ox + zc[s]*dx, oy + zc[s]*dy, oz + zc[s]*dz, sWf, w2f,
             fb0, fb1, fb2, fbd, rr0[s], rr1[s], rr2[s], dens[s]);
  }

  float dd[3];
#pragma unroll
  for (int s = 0; s < 3; ++s) {
    const int i = lane + 64*s;
    const float td = (i == NZ-1) ? 1e10f : fmaxf(zn[s] - zc[s], 0.f);
    dd[s] = fminf(dens[s] * (td * dnorm), 1e4f);
  }

  float excl[3];
  float offset = 0.f;
#pragma unroll
  for (int s = 0; s < 3; ++s) {
    const float incl = wave_incl_scan(dd[s], lane);
    excl[s] = offset + incl - dd[s];
    offset += __shfl(incl, 63);
  }

  __syncthreads();   // sZv0 ready (wave 0 wrote it above)

  float aw = 0.f, awz = 0.f, ac0 = 0.f, ac1 = 0.f, ac2 = 0.f, awz0 = 0.f;
#pragma unroll
  for (int s = 0; s < 3; ++s) {
    const int i = lane + 64*s;
    const float wgt = (1.f - expf(-dd[s])) * expf(-excl[s]);
    aw   += wgt;
    awz  += wgt * zc[s];
    ac0  += wgt * rr0[s];
    ac1  += wgt * rr1[s];
    ac2  += wgt * rr2[s];
    awz0 += wgt * sZv0[i];
  }
  aw  = wave_sum(aw);  awz = wave_sum(awz); ac0 = wave_sum(ac0);
  ac1 = wave_sum(ac1); ac2 = wave_sum(ac2); awz0 = wave_sum(awz0);

  if (lane == 0) {
    const float bk0 = bkgd[0], bk1 = bkgd[1], bk2 = bkgd[2];
    const float o0x = origins[0], o0y = origins[1], o0z = origins[2];
    const float d0x = dirs[0],    d0y = dirs[1],    d0z = dirs[2];
    const float oma = 1.f - aw;
    float* o = out + (size_t)ray * 16 + 8;
    o[0] = ac0 + bk0 * oma;
    o[1] = ac1 + bk1 * oma;
    o[2] = ac2 + bk2 * oma;
    o[3] = awz;                        // depth1
    o[4] = aw;                         // acc1
    o[5] = aw * o0x + awz0 * d0x;      // pts1
    o[6] = aw * o0y + awz0 * d0y;
    o[7] = aw * o0z + awz0 * d0z;
  }
}

extern "C" void kernel_launch(void* const* d_in, const int* in_sizes, int n_in,
                              void* d_out, int out_size, void* d_ws, size_t ws_size,
                              hipStream_t stream) {
  const float* origins = (const float*)d_in[0];
  const float* dirs    = (const float*)d_in[1];
  const float* nearp   = (const float*)d_in[2];
  const float* farp    = (const float*)d_in[3];
  const float* bkgd    = (const float*)d_in[4];
  const float* w1c  = (const float*)d_in[5];
  const float* b1c  = (const float*)d_in[6];
  const float* w2c  = (const float*)d_in[7];
  const float* b2c  = (const float*)d_in[8];
  const float* wrc  = (const float*)d_in[9];
  const float* brc  = (const float*)d_in[10];
  const float* wdc  = (const float*)d_in[11];
  const float* bdc  = (const float*)d_in[12];
  const float* w1f  = (const float*)d_in[13];
  const float* b1f  = (const float*)d_in[14];
  const float* w2f  = (const float*)d_in[15];
  const float* b2f_ = (const float*)d_in[16];
  const float* wrf  = (const float*)d_in[17];
  const float* brf  = (const float*)d_in[18];
  const float* wdf  = (const float*)d_in[19];
  const float* bdf  = (const float*)d_in[20];

  nerf_fused_kernel<<<NRAYS/4, 256, 0, stream>>>(
      origins, dirs, nearp, farp, bkgd,
      w1c, b1c, w2c, b2c, wrc, brc, wdc, bdc,
      w1f, b1f, w2f, b2f_, wrf, brf, wdf, bdf,
      (float*)d_out);
}